// Round 1
// baseline (5662.505 us; speedup 1.0000x reference)
//
#include <hip/hip_runtime.h>
#include <stdint.h>

#define GRID_Z 10
#define GRID_Y 400
#define GRID_X 352
#define NGRID (GRID_Z * GRID_Y * GRID_X)   // 1,408,000
#define NVOX 200000
#define CCH 128
#define MROI 64
#define GXD 64
#define GYD 32
#define GZD 4
#define GCELLS 8192                         // GXD*GYD*GZD

// Recompute a grid cell's world xyz exactly like the reference (fp32, no fma
// contraction so floor() boundaries match XLA's mul+add evaluation).
__device__ __forceinline__ void cell_xyz(const float* __restrict__ roi, int g,
                                         float& X, float& Y, float& Z) {
#pragma clang fp contract(off)
    int iz = g & 3;
    int iy = (g >> 2) & 31;
    int ix = g >> 7;
    float bx = roi[3] * 2.0f;   // EXTEND on x,y dims
    float by = roi[4] * 2.0f;
    float bz = roi[5];
    float lx = (ix + 0.5f) / 64.0f * bx - bx / 2.0f;
    float ly = (iy + 0.5f) / 32.0f * by - by / 2.0f;
    float lz = (iz + 0.5f) / 4.0f  * bz - bz / 2.0f;
    float c = cosf(roi[6]);
    float s = sinf(roi[6]);
    X = lx * c + ly * (-s) + roi[0];
    Y = lx * s + ly * c    + roi[1];
    Z = lz + roi[2];
}

__global__ void k_init(int* __restrict__ v2p, unsigned long long* __restrict__ best) {
    int i = blockIdx.x * 256 + threadIdx.x;   // grid sized to exactly NGRID
    v2p[i] = -1;
    if (i < MROI) best[i] = 0ull;
}

__global__ void k_scatter(const int* __restrict__ vcoords, int* __restrict__ v2p) {
    int i = blockIdx.x * 256 + threadIdx.x;
    if (i >= NVOX) return;
    int z = vcoords[i * 4 + 1];
    int y = vcoords[i * 4 + 2];
    int x = vcoords[i * 4 + 3];
    // Duplicate coords: XLA scatter applies updates in order -> last (max idx) wins.
    atomicMax(&v2p[(z * GRID_Y + y) * GRID_X + x], i);
}

__global__ void k_pidx(const float* __restrict__ rois, const int* __restrict__ v2p,
                       int* __restrict__ pidx) {
#pragma clang fp contract(off)
    int g = blockIdx.x * 256 + threadIdx.x;   // [0, GCELLS)
    int m = blockIdx.y;
    const float* roi = rois + m * 7;
    float X, Y, Z;
    cell_xyz(roi, g, X, Y, Z);
    // coords = floor((xyz - PC_MIN)/VOXEL_SIZE); coords = floor(coords/4)
    float fx = floorf((X - 0.0f)    / 0.05f);
    float fy = floorf((Y - (-40.0f)) / 0.05f);
    float fz = floorf((Z - (-3.0f))  / 0.1f);
    int cx = (int)floorf(fx / 4.0f);
    int cy = (int)floorf(fy / 4.0f);
    int cz = (int)floorf(fz / 4.0f);
    int p = -1;
    if (cz >= 0 && cz < GRID_Z && cy >= 0 && cy < GRID_Y && cx >= 0 && cx < GRID_X)
        p = v2p[(cz * GRID_Y + cy) * GRID_X + cx];
    pidx[m * GCELLS + g] = p;
}

// One wave (64 lanes) per output cell; lane covers channels {2*lane, 2*lane+1}.
// Proto (147x128 fp32 = 75 KB) staged in LDS in two kx-chunks of <= 43 KB.
__global__ __launch_bounds__(256) void k_score(
        const float* __restrict__ vfeat, const float* __restrict__ fproto,
        const int* __restrict__ pidx, unsigned long long* __restrict__ best) {
    __shared__ float sproto[4 * 21 * CCH];    // 10752 floats = 43 KB

    int tid  = threadIdx.x;
    int lane = tid & 63;
    int wave = tid >> 6;
    int cell = blockIdx.x * 4 + wave;         // [0, MROI*GCELLS)
    int m = cell >> 13;
    int g = cell & (GCELLS - 1);
    int gx = g >> 7;
    int gy = (g >> 2) & 31;
    int gz = g & 3;
    const int* pid = pidx + m * GCELLS;

    float2 acc = make_float2(0.0f, 0.0f);

    for (int pass = 0; pass < 2; ++pass) {
        int kx0 = pass ? 4 : 0;
        int nkx = pass ? 3 : 4;
        __syncthreads();                       // previous chunk's compute done
        {   // cooperative load: nkx*21*128 floats, float4-wide
            const float4* src = (const float4*)(fproto + kx0 * 21 * CCH);
            float4* dst = (float4*)sproto;
            int n4 = nkx * 21 * CCH / 4;
            for (int i = tid; i < n4; i += 256) dst[i] = src[i];
        }
        __syncthreads();

        for (int kx = 0; kx < nkx; ++kx) {
            int nx = gx + kx0 + kx - 3;
            if ((unsigned)nx >= (unsigned)GXD) continue;
            for (int ky = 0; ky < 7; ++ky) {
                int ny = gy + ky - 3;
                if ((unsigned)ny >= (unsigned)GYD) continue;
                int pbase = (nx * GYD + ny) * GZD;
                const float* prow = sproto + (kx * 21 + ky * 3) * CCH;
                for (int kz = 0; kz < 3; ++kz) {
                    int nz = gz + kz - 1;
                    if ((unsigned)nz >= (unsigned)GZD) continue;
                    int p = pid[pbase + nz];
                    if (p < 0) continue;
                    float2 f = ((const float2*)(vfeat + (size_t)p * CCH))[lane];
                    float2 w = ((const float2*)(prow + kz * CCH))[lane];
                    acc.x += f.x * w.x;
                    acc.y += f.y * w.y;
                }
            }
        }
    }

    float v = acc.x + acc.y;
    #pragma unroll
    for (int off = 32; off > 0; off >>= 1) v += __shfl_down(v, off, 64);

    if (lane == 0) {
        unsigned ub  = __float_as_uint(v);
        unsigned key = (ub & 0x80000000u) ? ~ub : (ub | 0x80000000u);  // order-preserving
        unsigned long long packed =
            ((unsigned long long)key << 32) | (unsigned)(GCELLS - 1 - g);  // ties -> smallest g
        atomicMax(best + m, packed);
    }
}

__global__ void k_final(const float* __restrict__ rois, const float* __restrict__ pbox,
                        const unsigned long long* __restrict__ best,
                        float* __restrict__ out) {
    int m = threadIdx.x;
    if (m >= MROI) return;
    unsigned long long p = best[m];
    int g = (GCELLS - 1) - (int)(unsigned)(p & 0xFFFFFFFFu);
    float X, Y, Z;
    cell_xyz(rois + m * 7, g, X, Y, Z);
    out[m * 7 + 0] = X;
    out[m * 7 + 1] = Y;
    out[m * 7 + 2] = Z;
    out[m * 7 + 3] = pbox[3];
    out[m * 7 + 4] = pbox[4];
    out[m * 7 + 5] = pbox[5];
    out[m * 7 + 6] = pbox[6];
}

extern "C" void kernel_launch(void* const* d_in, const int* in_sizes, int n_in,
                              void* d_out, int out_size, void* d_ws, size_t ws_size,
                              hipStream_t stream) {
    const float* rois    = (const float*)d_in[0];
    const float* pbox    = (const float*)d_in[1];
    const float* vfeat   = (const float*)d_in[2];
    const float* fproto  = (const float*)d_in[3];
    const int*   vcoords = (const int*)d_in[4];
    float* out = (float*)d_out;

    int* v2p  = (int*)d_ws;                       // NGRID ints          (5.63 MB)
    int* pidx = v2p + NGRID;                      // MROI*GCELLS ints    (2.10 MB)
    unsigned long long* best =
        (unsigned long long*)(pidx + MROI * GCELLS);  // 64 x u64 (8B-aligned)

    k_init   <<<NGRID / 256, 256, 0, stream>>>(v2p, best);
    k_scatter<<<(NVOX + 255) / 256, 256, 0, stream>>>(vcoords, v2p);
    k_pidx   <<<dim3(GCELLS / 256, MROI), 256, 0, stream>>>(rois, v2p, pidx);
    k_score  <<<MROI * GCELLS / 4, 256, 0, stream>>>(vfeat, fproto, pidx, best);
    k_final  <<<1, 64, 0, stream>>>(rois, pbox, best, out);
}

// Round 2
// 2788.005 us; speedup vs baseline: 2.0310x; 2.0310x over previous
//
#include <hip/hip_runtime.h>
#include <stdint.h>

#define GRID_Z 10
#define GRID_Y 400
#define GRID_X 352
#define NGRID (GRID_Z * GRID_Y * GRID_X)   // 1,408,000
#define NVOX 200000
#define CCH 128
#define MROI 64
#define GXD 64
#define GYD 32
#define GZD 4
#define GCELLS 8192                         // GXD*GYD*GZD

// Recompute a grid cell's world xyz exactly like the reference (fp32, no fma
// contraction so floor() boundaries match XLA's mul+add evaluation).
__device__ __forceinline__ void cell_xyz(const float* __restrict__ roi, int g,
                                         float& X, float& Y, float& Z) {
#pragma clang fp contract(off)
    int iz = g & 3;
    int iy = (g >> 2) & 31;
    int ix = g >> 7;
    float bx = roi[3] * 2.0f;   // EXTEND on x,y dims
    float by = roi[4] * 2.0f;
    float bz = roi[5];
    float lx = (ix + 0.5f) / 64.0f * bx - bx / 2.0f;
    float ly = (iy + 0.5f) / 32.0f * by - by / 2.0f;
    float lz = (iz + 0.5f) / 4.0f  * bz - bz / 2.0f;
    float c = cosf(roi[6]);
    float s = sinf(roi[6]);
    X = lx * c + ly * (-s) + roi[0];
    Y = lx * s + ly * c    + roi[1];
    Z = lz + roi[2];
}

__global__ void k_init(int* __restrict__ v2p, unsigned long long* __restrict__ best) {
    int i = blockIdx.x * 256 + threadIdx.x;   // grid sized to exactly NGRID
    v2p[i] = -1;
    if (i < MROI) best[i] = 0ull;
}

__global__ void k_scatter(const int* __restrict__ vcoords, int* __restrict__ v2p) {
    int i = blockIdx.x * 256 + threadIdx.x;
    if (i >= NVOX) return;
    int z = vcoords[i * 4 + 1];
    int y = vcoords[i * 4 + 2];
    int x = vcoords[i * 4 + 3];
    // Duplicate coords: XLA scatter applies updates in order -> last (max idx) wins.
    atomicMax(&v2p[(z * GRID_Y + y) * GRID_X + x], i);
}

__global__ void k_pidx(const float* __restrict__ rois, const int* __restrict__ v2p,
                       int* __restrict__ pidx) {
#pragma clang fp contract(off)
    int g = blockIdx.x * 256 + threadIdx.x;   // [0, GCELLS)
    int m = blockIdx.y;
    const float* roi = rois + m * 7;
    float X, Y, Z;
    cell_xyz(roi, g, X, Y, Z);
    float fx = floorf((X - 0.0f)     / 0.05f);
    float fy = floorf((Y - (-40.0f)) / 0.05f);
    float fz = floorf((Z - (-3.0f))  / 0.1f);
    int cx = (int)floorf(fx / 4.0f);
    int cy = (int)floorf(fy / 4.0f);
    int cz = (int)floorf(fz / 4.0f);
    int p = -1;
    if (cz >= 0 && cz < GRID_Z && cy >= 0 && cy < GRID_Y && cx >= 0 && cx < GRID_X)
        p = v2p[(cz * GRID_Y + cy) * GRID_X + cx];
    pidx[m * GCELLS + g] = p;
}

// One half-wave (32 lanes) per output cell, lane covers 4 channels (float4).
// Phase 1: ballot-compact the valid (p, k) taps (bounds + p>=0; ~14% survive)
// into an LDS list. Phase 2: walk the list 4 taps at a time -> ~8 global
// loads in flight per wave (vs ~1 in the serial version).
__global__ __launch_bounds__(256) void k_score(
        const float* __restrict__ vfeat, const float* __restrict__ fproto,
        const int* __restrict__ pidx, unsigned long long* __restrict__ best) {
    __shared__ float sproto[4 * 21 * CCH];    // 43008 B (kx-chunked proto)
    __shared__ unsigned slist[8][96];         // per-cell compact tap list, 3 KB

    int tid  = threadIdx.x;
    int lane = tid & 63;
    int wave = tid >> 6;
    int half = lane >> 5;
    int l32  = lane & 31;
    int slot = wave * 2 + half;               // 0..7: which cell of this block
    int cell = blockIdx.x * 8 + slot;         // [0, MROI*GCELLS)
    int m = cell >> 13;
    int g = cell & (GCELLS - 1);
    int gx = g >> 7;
    int gy = (g >> 2) & 31;
    int gz = g & 3;
    const int*    pid = pidx + m * GCELLS;
    const float4* vf4 = (const float4*)vfeat;
    const float4* sp4 = (const float4*)sproto;

    float4 acc = make_float4(0.f, 0.f, 0.f, 0.f);

    for (int pass = 0; pass < 2; ++pass) {
        const int kx0 = pass ? 4 : 0;
        const int nk  = pass ? 63 : 84;       // taps in this kx-chunk
        __syncthreads();                      // previous chunk's compute done
        {   // cooperative proto chunk load, float4-wide
            const float4* src = (const float4*)(fproto + kx0 * 21 * CCH);
            float4* dst = (float4*)sproto;
            int n4 = nk * (CCH / 4);
            for (int i = tid; i < n4; i += 256) dst[i] = src[i];
        }
        __syncthreads();

        // ---- Phase 1: parallel validity + ballot compaction ----
        int cnt = 0;                          // half-wave-uniform register
        for (int r = 0; r * 32 < nk; ++r) {
            int t = r * 32 + l32;             // pass-local tap id
            int p = -1;
            if (t < nk) {
                int kx  = t / 21;
                int rem = t - kx * 21;
                int ky  = rem / 3;
                int kz  = rem - ky * 3;
                int nx = gx + kx0 + kx - 3;
                int ny = gy + ky - 3;
                int nz = gz + kz - 1;
                if ((unsigned)nx < (unsigned)GXD && (unsigned)ny < (unsigned)GYD &&
                    (unsigned)nz < (unsigned)GZD)
                    p = pid[(nx * GYD + ny) * GZD + nz];
            }
            bool v = p >= 0;
            unsigned long long bal = __ballot(v);
            unsigned bm = (unsigned)(bal >> (half * 32));
            if (v) {
                int pos = __popc(bm & ((1u << l32) - 1u));
                slist[slot][cnt + pos] = ((unsigned)p << 8) | (unsigned)t;
            }
            cnt += __popc(bm);
        }
        // sentinel pad so the 4-wide reads below never index garbage
        if (l32 < 4) slist[slot][cnt + l32] = 0u;

        // ---- Phase 2: 4 taps per iteration, 8 loads in flight ----
        for (int i = 0; i < cnt; i += 4) {
            uint4 e = *(const uint4*)&slist[slot][i];   // broadcast b128
            unsigned ev0 = e.x, ev1 = e.y, ev2 = e.z, ev3 = e.w;
            #pragma unroll
            for (int j = 0; j < 4; ++j) {
                unsigned en = (j == 0) ? ev0 : (j == 1) ? ev1 : (j == 2) ? ev2 : ev3;
                int p = (int)(en >> 8);
                int t = (int)(en & 255u);
                float4 f = vf4[(size_t)p * (CCH / 4) + l32];
                float4 w = sp4[t * (CCH / 4) + l32];
                float msk = (i + j < cnt) ? 1.0f : 0.0f;
                acc.x += f.x * w.x * msk;
                acc.y += f.y * w.y * msk;
                acc.z += f.z * w.z * msk;
                acc.w += f.w * w.w * msk;
            }
        }
    }

    // reduce across the half-wave (lane 0 / lane 32 end up with the two sums)
    float s = acc.x + acc.y + acc.z + acc.w;
    #pragma unroll
    for (int off = 16; off > 0; off >>= 1) s += __shfl_down(s, off, 64);

    if (l32 == 0) {
        unsigned ub  = __float_as_uint(s);
        unsigned key = (ub & 0x80000000u) ? ~ub : (ub | 0x80000000u);  // order-preserving
        unsigned long long packed =
            ((unsigned long long)key << 32) | (unsigned)(GCELLS - 1 - g);  // ties -> smallest g
        atomicMax(best + m, packed);
    }
}

__global__ void k_final(const float* __restrict__ rois, const float* __restrict__ pbox,
                        const unsigned long long* __restrict__ best,
                        float* __restrict__ out) {
    int m = threadIdx.x;
    if (m >= MROI) return;
    unsigned long long p = best[m];
    int g = (GCELLS - 1) - (int)(unsigned)(p & 0xFFFFFFFFu);
    float X, Y, Z;
    cell_xyz(rois + m * 7, g, X, Y, Z);
    out[m * 7 + 0] = X;
    out[m * 7 + 1] = Y;
    out[m * 7 + 2] = Z;
    out[m * 7 + 3] = pbox[3];
    out[m * 7 + 4] = pbox[4];
    out[m * 7 + 5] = pbox[5];
    out[m * 7 + 6] = pbox[6];
}

extern "C" void kernel_launch(void* const* d_in, const int* in_sizes, int n_in,
                              void* d_out, int out_size, void* d_ws, size_t ws_size,
                              hipStream_t stream) {
    const float* rois    = (const float*)d_in[0];
    const float* pbox    = (const float*)d_in[1];
    const float* vfeat   = (const float*)d_in[2];
    const float* fproto  = (const float*)d_in[3];
    const int*   vcoords = (const int*)d_in[4];
    float* out = (float*)d_out;

    int* v2p  = (int*)d_ws;                       // NGRID ints          (5.63 MB)
    int* pidx = v2p + NGRID;                      // MROI*GCELLS ints    (2.10 MB)
    unsigned long long* best =
        (unsigned long long*)(pidx + MROI * GCELLS);  // 64 x u64 (8B-aligned)

    k_init   <<<NGRID / 256, 256, 0, stream>>>(v2p, best);
    k_scatter<<<(NVOX + 255) / 256, 256, 0, stream>>>(vcoords, v2p);
    k_pidx   <<<dim3(GCELLS / 256, MROI), 256, 0, stream>>>(rois, v2p, pidx);
    k_score  <<<MROI * GCELLS / 8, 256, 0, stream>>>(vfeat, fproto, pidx, best);
    k_final  <<<1, 64, 0, stream>>>(rois, pbox, best, out);
}